// Round 4
// baseline (467.152 us; speedup 1.0000x reference)
//
#include <hip/hip_runtime.h>

namespace {

constexpr int B = 64;
constexpr int N = 64;
constexpr int D = 64;
constexpr int E = 2 * D + 1;  // 129
constexpr int BND = B * N * D;

// Runs once: packs adjacency tables + readout weights into workspace.
__global__ __launch_bounds__(64) void k_prep(
    const float* __restrict__ ew,   // [N][N]
    uint4* __restrict__ nbr4,       // [N] 16 packed neighbor ids (bytes)
    float* __restrict__ degf,       // [N]
    float* __restrict__ cwg,        // [N] readout weights
    int* __restrict__ cntg,         // [N]
    unsigned char* __restrict__ nfull)  // [N][N] full list (tail fallback)
{
  const int t = threadIdx.x;  // 0..63 = node
  unsigned long long lo = 0ull, hi = 0ull;
  int c = 0;
  float rowsum = 0.0f;
  for (int j = 0; j < N; ++j) {
    const float v = ew[t * N + j];
    rowsum += v;
    if (v > 0.0f) {
      if (c < 8)       lo |= (unsigned long long)j << (c * 8);
      else if (c < 16) hi |= (unsigned long long)j << ((c - 8) * 8);
      nfull[t * N + c] = (unsigned char)j;
      ++c;
    }
  }
  uint4 w;
  w.x = (unsigned)(lo & 0xffffffffu);
  w.y = (unsigned)(lo >> 32);
  w.z = (unsigned)(hi & 0xffffffffu);
  w.w = (unsigned)(hi >> 32);
  nbr4[t] = w;
  cntg[t] = c;
  degf[t] = (float)c;

  float tot = rowsum;
#pragma unroll
  for (int off = 32; off >= 1; off >>= 1) tot += __shfl_xor(tot, off, 64);
  cwg[t] = rowsum / (tot + 1e-8f);
}

// Grid N*N; block 256. One block per (i,j); early-exit on non-edge.
// Wave w owns d-chunk [16w,16w+16): W rows are full 64B s_load_dwordx16.
__global__ __launch_bounds__(256) void k_msg(
    const float* __restrict__ sin,   // [B][N][D] (x for layer 0, s otherwise)
    const float* __restrict__ ew,    // [N][N]
    const float* __restrict__ Wm,    // [N][N][E][D]  (layer slice)
    const float* __restrict__ bm,    // [N][N][D]     (layer slice)
    float* __restrict__ agg)         // [B][N][D]
{
  const int ij = blockIdx.x;
  const float w = ew[ij];
  if (w == 0.0f) return;  // uniform across block
  const int i = ij >> 6;
  const int j = ij & 63;

  __shared__ float siT[D][B];  // siT[k][b] = sin[b][i][k]
  __shared__ float sjT[D][B];

  const int t = threadIdx.x;
  {
    const int bb = t >> 2;   // 0..63
    const int q  = t & 3;    // 0..3
    const float* ps = sin + ((size_t)bb * N + i) * D;
    const float* pq = sin + ((size_t)bb * N + j) * D;
#pragma unroll
    for (int kc = 0; kc < 4; ++kc) {
      const int k0 = kc * 16 + q * 4;
      float4 v = *(const float4*)(ps + k0);
      siT[k0 + 0][bb] = v.x;
      siT[k0 + 1][bb] = v.y;
      siT[k0 + 2][bb] = v.z;
      siT[k0 + 3][bb] = v.w;
      float4 u2 = *(const float4*)(pq + k0);
      sjT[k0 + 0][bb] = u2.x;
      sjT[k0 + 1][bb] = u2.y;
      sjT[k0 + 2][bb] = u2.z;
      sjT[k0 + 3][bb] = u2.w;
    }
  }
  __syncthreads();

  const int b  = t & 63;                                       // lane = batch
  const int d0 = __builtin_amdgcn_readfirstlane(t >> 6) * 16;  // wave-uniform
  const float* __restrict__ Wp = Wm + (size_t)ij * (E * D);

  float acc[16];
#pragma unroll
  for (int u = 0; u < 16; ++u)
    acc[u] = w * Wp[(size_t)(2 * D) * D + d0 + u] + bm[(size_t)ij * D + d0 + u];

#pragma unroll 4
  for (int k = 0; k < D; ++k) {
    const float a  = siT[k][b];
    const float c2 = sjT[k][b];
    const float* __restrict__ w1 = Wp + (size_t)k * D + d0;        // feat_i
    const float* __restrict__ w2 = Wp + (size_t)(D + k) * D + d0;  // feat_j
#pragma unroll
    for (int u = 0; u < 16; ++u)
      acc[u] += a * w1[u] + c2 * w2[u];
  }

  float* ap = agg + ((size_t)b * N + i) * D + d0;
#pragma unroll
  for (int u = 0; u < 16; ++u)
    atomicAdd(ap + u, acc[u]);
}

// One block per batch b: update MLP + residual mix, sequential node scan in
// LDS; zeroes agg for the next layer. LAST variant fuses readout + projection.
template <bool LAST>
__global__ __launch_bounds__(256) void k_upd(
    const float* __restrict__ sin,  // [B][N][D]
    float* __restrict__ s,          // [B][N][D] out (non-LAST)
    float* __restrict__ agg,        // [B][N][D]; zeroed here (non-LAST)
    const uint4* __restrict__ nbr4,
    const float* __restrict__ degg,
    const float* __restrict__ cwg,
    const int* __restrict__ cntg,
    const unsigned char* __restrict__ nfull,
    const float* __restrict__ Wu,   // [2D][D] (layer slice)
    const float* __restrict__ bu,   // [D]
    const float* __restrict__ Wo,   // [D][D]
    const float* __restrict__ bo,   // [D]
    float* __restrict__ out)        // [B][D]
{
  const int b = blockIdx.x;
  const int t = threadIdx.x;

  __shared__ float catT[2 * D][N];   // catT[k][i]: k<D -> sin, k>=D -> agg
  __shared__ float sb[N][D + 1];     // padded scan state
  __shared__ uint4 nbrL[N];
  __shared__ float degL[N];
  __shared__ float cwL[N];
  __shared__ int   cntL[N];

  {
    const int ii = t >> 2;
    const int q  = t & 3;
    const float* ps = sin + ((size_t)b * N + ii) * D;
    float*       pa = agg + ((size_t)b * N + ii) * D;
#pragma unroll
    for (int kc = 0; kc < 4; ++kc) {
      const int k0 = kc * 16 + q * 4;
      float4 v = *(const float4*)(ps + k0);
      catT[k0 + 0][ii] = v.x;
      catT[k0 + 1][ii] = v.y;
      catT[k0 + 2][ii] = v.z;
      catT[k0 + 3][ii] = v.w;
      float4 u2 = *(const float4*)(pa + k0);
      catT[D + k0 + 0][ii] = u2.x;
      catT[D + k0 + 1][ii] = u2.y;
      catT[D + k0 + 2][ii] = u2.z;
      catT[D + k0 + 3][ii] = u2.w;
      if (!LAST) *(float4*)(pa + k0) = make_float4(0.f, 0.f, 0.f, 0.f);
    }
  }
  if (t < N) {
    nbrL[t] = nbr4[t];
    degL[t] = degg[t];
    cntL[t] = cntg[t];
    if (LAST) cwL[t] = cwg[t];
  }
  __syncthreads();

  // upd GEMM: lane = i, wave-uniform d-chunk
  const int i  = t & 63;
  const int d0 = __builtin_amdgcn_readfirstlane(t >> 6) * 16;

  float acc[16];
#pragma unroll
  for (int u = 0; u < 16; ++u) acc[u] = bu[d0 + u];

#pragma unroll 4
  for (int k = 0; k < 2 * D; ++k) {
    const float a = catT[k][i];
    const float* __restrict__ wr = Wu + (size_t)k * D + d0;
#pragma unroll
    for (int u = 0; u < 16; ++u) acc[u] += a * wr[u];
  }
#pragma unroll
  for (int u = 0; u < 16; ++u)
    sb[i][d0 + u] = 0.9f * acc[u] + 0.1f * catT[d0 + u][i];
  __syncthreads();

  // sequential scan; lane d owns column d of sb (wave 0 only)
  if (t < N) {
    const int d = t;
    uint4 w  = nbrL[0];
    int   c  = cntL[0];
    float dg = degL[0];
    for (int ii = 0; ii < N; ++ii) {
      uint4 wn = w; int cn = c; float dgn = dg;
      if (ii < N - 1) {
        wn  = nbrL[ii + 1];
        cn  = cntL[ii + 1];
        dgn = degL[ii + 1];
      }
      const unsigned wd[4] = {w.x, w.y, w.z, w.w};
      float nb = 0.0f;
#pragma unroll
      for (int q = 0; q < 8; ++q) {
        const int idx = (int)((wd[q >> 2] >> ((q & 3) * 8)) & 63u);
        const float v = sb[idx][d];
        nb += (q < c) ? v : 0.0f;
      }
      if (c > 8) {
#pragma unroll
        for (int q = 8; q < 16; ++q) {
          const int idx = (int)((wd[q >> 2] >> ((q & 3) * 8)) & 63u);
          const float v = sb[idx][d];
          nb += (q < c) ? v : 0.0f;
        }
        for (int q = 16; q < c; ++q) nb += sb[nfull[ii * N + q]][d];  // rare
      }
      const float avg = nb / fmaxf(dg, 1.0f);
      const float cur = sb[ii][d];
      sb[ii][d] = (dg > 0.0f) ? (0.95f * cur + 0.05f * avg) : cur;
      w = wn; c = cn; dg = dgn;
    }
    if (LAST) {
      float g = 0.0f;
      for (int i2 = 0; i2 < N; ++i2) g += cwL[i2] * sb[i2][d];

      float o = bo[d];
      for (int k2 = 0; k2 < D; ++k2) o += __shfl(g, k2, 64) * Wo[k2 * D + d];
      out[(size_t)b * D + d] = o;
    }
  }

  if (!LAST) {
    __syncthreads();
    const int ii = t >> 2;
    const int q  = t & 3;
    float* ps = s + ((size_t)b * N + ii) * D;
#pragma unroll
    for (int kc = 0; kc < 4; ++kc) {
      const int k0 = kc * 16 + q * 4;
      float4 v;
      v.x = sb[ii][k0 + 0];
      v.y = sb[ii][k0 + 1];
      v.z = sb[ii][k0 + 2];
      v.w = sb[ii][k0 + 3];
      *(float4*)(ps + k0) = v;
    }
  }
}

}  // namespace

extern "C" void kernel_launch(void* const* d_in, const int* in_sizes, int n_in,
                              void* d_out, int out_size, void* d_ws, size_t ws_size,
                              hipStream_t stream)
{
  const float* x  = (const float*)d_in[0];
  const float* ew = (const float*)d_in[1];
  const float* Wm = (const float*)d_in[2];
  const float* bm = (const float*)d_in[3];
  const float* Wu = (const float*)d_in[4];
  const float* bu = (const float*)d_in[5];
  const float* Wo = (const float*)d_in[6];
  const float* bo = (const float*)d_in[7];
  float* out = (float*)d_out;

  float* s   = (float*)d_ws;
  float* agg = s + BND;
  uint4* nbr4 = (uint4*)(agg + BND);
  float* degf = (float*)(nbr4 + N);
  float* cwg  = degf + N;
  int*   cntg = (int*)(cwg + N);
  unsigned char* nfull = (unsigned char*)(cntg + N);

  const int L = in_sizes[2] / (N * N * E * D);  // = 3

  hipMemsetAsync(agg, 0, (size_t)BND * sizeof(float), stream);
  k_prep<<<1, 64, 0, stream>>>(ew, nbr4, degf, cwg, cntg, nfull);

  for (int l = 0; l < L; ++l) {
    const float* sin_p = (l == 0) ? x : s;
    k_msg<<<N * N, 256, 0, stream>>>(
        sin_p, ew,
        Wm + (size_t)l * N * N * E * D,
        bm + (size_t)l * N * N * D,
        agg);
    if (l < L - 1) {
      k_upd<false><<<B, 256, 0, stream>>>(
          sin_p, s, agg, nbr4, degf, cwg, cntg, nfull,
          Wu + (size_t)l * 2 * D * D, bu + (size_t)l * D,
          Wo, bo, out);
    } else {
      k_upd<true><<<B, 256, 0, stream>>>(
          sin_p, s, agg, nbr4, degf, cwg, cntg, nfull,
          Wu + (size_t)l * 2 * D * D, bu + (size_t)l * D,
          Wo, bo, out);
    }
  }
}

// Round 5
// 201.304 us; speedup vs baseline: 2.3206x; 2.3206x over previous
//
#include <hip/hip_runtime.h>

namespace {

constexpr int B = 64;
constexpr int N = 64;
constexpr int D = 64;
constexpr int E = 2 * D + 1;  // 129
constexpr int BND = B * N * D;

// Runs once: adjacency tables, readout weights, edge->slot mapping.
// Slots are assigned row-major, so node i's edges are slots
// rowbase[i] .. rowbase[i]+cnt[i]-1 (contiguous).
__global__ __launch_bounds__(64) void k_prep(
    const float* __restrict__ ew,   // [N][N]
    uint4* __restrict__ nbr4,       // [N] 16 packed neighbor ids (bytes)
    float* __restrict__ degf,       // [N]
    float* __restrict__ cwg,        // [N] readout weights
    int* __restrict__ cntg,         // [N]
    int* __restrict__ rowbaseg,     // [N]
    unsigned char* __restrict__ nfull,  // [N][N] full list (tail fallback)
    int* __restrict__ slotIdx)      // [N][N] edge slot (valid where ew>0)
{
  const int t = threadIdx.x;  // 0..63 = node

  // pass 1: per-row edge count -> exclusive prefix = row base slot
  int rc = 0;
  for (int j = 0; j < N; ++j) rc += (ew[t * N + j] > 0.0f) ? 1 : 0;
  int pre = rc;
#pragma unroll
  for (int off = 1; off < 64; off <<= 1) {
    int v = __shfl_up(pre, off, 64);
    if (t >= off) pre += v;
  }
  const int base = pre - rc;  // exclusive prefix
  rowbaseg[t] = base;

  // pass 2: pack neighbor ids, assign slots
  unsigned long long lo = 0ull, hi = 0ull;
  int c = 0;
  float rowsum = 0.0f;
  for (int j = 0; j < N; ++j) {
    const float v = ew[t * N + j];
    rowsum += v;
    if (v > 0.0f) {
      slotIdx[t * N + j] = base + c;
      if (c < 8)       lo |= (unsigned long long)j << (c * 8);
      else if (c < 16) hi |= (unsigned long long)j << ((c - 8) * 8);
      nfull[t * N + c] = (unsigned char)j;
      ++c;
    }
  }
  uint4 w;
  w.x = (unsigned)(lo & 0xffffffffu);
  w.y = (unsigned)(lo >> 32);
  w.z = (unsigned)(hi & 0xffffffffu);
  w.w = (unsigned)(hi >> 32);
  nbr4[t] = w;
  cntg[t] = c;
  degf[t] = (float)c;

  float tot = rowsum;
#pragma unroll
  for (int off = 32; off >= 1; off >>= 1) tot += __shfl_xor(tot, off, 64);
  cwg[t] = rowsum / (tot + 1e-8f);
}

// Grid N*N; block 256. One block per (i,j); early-exit on non-edge.
// Plain-stores the per-edge message block to msg[slot][b][d] (NO atomics).
__global__ __launch_bounds__(256) void k_msg(
    const float* __restrict__ sin,   // [B][N][D] (x for layer 0, s otherwise)
    const float* __restrict__ ew,    // [N][N]
    const float* __restrict__ Wm,    // [N][N][E][D]  (layer slice)
    const float* __restrict__ bm,    // [N][N][D]     (layer slice)
    const int* __restrict__ slotIdx, // [N][N]
    float* __restrict__ msg)         // [slot][B][D]
{
  const int ij = blockIdx.x;
  const float w = ew[ij];
  if (w == 0.0f) return;  // uniform across block
  const int i = ij >> 6;
  const int j = ij & 63;

  __shared__ float siT[D][B];  // siT[k][b] = sin[b][i][k]
  __shared__ float sjT[D][B];

  const int t = threadIdx.x;
  {
    const int bb = t >> 2;   // 0..63
    const int q  = t & 3;    // 0..3
    const float* ps = sin + ((size_t)bb * N + i) * D;
    const float* pq = sin + ((size_t)bb * N + j) * D;
#pragma unroll
    for (int kc = 0; kc < 4; ++kc) {
      const int k0 = kc * 16 + q * 4;
      float4 v = *(const float4*)(ps + k0);
      siT[k0 + 0][bb] = v.x;
      siT[k0 + 1][bb] = v.y;
      siT[k0 + 2][bb] = v.z;
      siT[k0 + 3][bb] = v.w;
      float4 u2 = *(const float4*)(pq + k0);
      sjT[k0 + 0][bb] = u2.x;
      sjT[k0 + 1][bb] = u2.y;
      sjT[k0 + 2][bb] = u2.z;
      sjT[k0 + 3][bb] = u2.w;
    }
  }
  __syncthreads();

  const int b  = t & 63;                                       // lane = batch
  const int d0 = __builtin_amdgcn_readfirstlane(t >> 6) * 16;  // wave-uniform
  const float* __restrict__ Wp = Wm + (size_t)ij * (E * D);
  const int slot = slotIdx[ij];

  float acc[16];
#pragma unroll
  for (int u = 0; u < 16; ++u)
    acc[u] = w * Wp[(size_t)(2 * D) * D + d0 + u] + bm[(size_t)ij * D + d0 + u];

#pragma unroll 4
  for (int k = 0; k < D; ++k) {
    const float a  = siT[k][b];
    const float c2 = sjT[k][b];
    const float* __restrict__ w1 = Wp + (size_t)k * D + d0;        // feat_i
    const float* __restrict__ w2 = Wp + (size_t)(D + k) * D + d0;  // feat_j
#pragma unroll
    for (int u = 0; u < 16; ++u)
      acc[u] += a * w1[u] + c2 * w2[u];
  }

  float* mp = msg + ((size_t)slot * B + b) * D + d0;
#pragma unroll
  for (int u = 0; u < 16; u += 4)
    *(float4*)(mp + u) = make_float4(acc[u], acc[u + 1], acc[u + 2], acc[u + 3]);
}

// One block per batch b: sums neighbor msg slots during staging (replaces
// agg), update MLP + residual mix, sequential node scan in LDS.
// LAST variant fuses readout + output projection.
template <bool LAST>
__global__ __launch_bounds__(256) void k_upd(
    const float* __restrict__ sin,  // [B][N][D]
    float* __restrict__ s,          // [B][N][D] out (non-LAST)
    const float* __restrict__ msg,  // [slot][B][D]
    const uint4* __restrict__ nbr4,
    const float* __restrict__ degg,
    const float* __restrict__ cwg,
    const int* __restrict__ cntg,
    const int* __restrict__ rowbaseg,
    const unsigned char* __restrict__ nfull,
    const float* __restrict__ Wu,   // [2D][D] (layer slice)
    const float* __restrict__ bu,   // [D]
    const float* __restrict__ Wo,   // [D][D]
    const float* __restrict__ bo,   // [D]
    float* __restrict__ out)        // [B][D]
{
  const int b = blockIdx.x;
  const int t = threadIdx.x;

  __shared__ float catT[2 * D][N];   // catT[k][i]: k<D -> sin, k>=D -> agg
  __shared__ float sb[N][D + 1];     // padded scan state
  __shared__ uint4 nbrL[N];
  __shared__ float degL[N];
  __shared__ float cwL[N];
  __shared__ int   cntL[N];

  {
    const int ii = t >> 2;
    const int q  = t & 3;
    const float* ps = sin + ((size_t)b * N + ii) * D;
    const int cI = cntg[ii];
    const int rb = rowbaseg[ii];

    float4 a4[4] = {make_float4(0.f, 0.f, 0.f, 0.f),
                    make_float4(0.f, 0.f, 0.f, 0.f),
                    make_float4(0.f, 0.f, 0.f, 0.f),
                    make_float4(0.f, 0.f, 0.f, 0.f)};
    for (int e = 0; e < cI; ++e) {
      const float* pm = msg + ((size_t)(rb + e) * B + b) * D;
#pragma unroll
      for (int kc = 0; kc < 4; ++kc) {
        const float4 v = *(const float4*)(pm + kc * 16 + q * 4);
        a4[kc].x += v.x; a4[kc].y += v.y; a4[kc].z += v.z; a4[kc].w += v.w;
      }
    }
#pragma unroll
    for (int kc = 0; kc < 4; ++kc) {
      const int k0 = kc * 16 + q * 4;
      float4 v = *(const float4*)(ps + k0);
      catT[k0 + 0][ii] = v.x;
      catT[k0 + 1][ii] = v.y;
      catT[k0 + 2][ii] = v.z;
      catT[k0 + 3][ii] = v.w;
      catT[D + k0 + 0][ii] = a4[kc].x;
      catT[D + k0 + 1][ii] = a4[kc].y;
      catT[D + k0 + 2][ii] = a4[kc].z;
      catT[D + k0 + 3][ii] = a4[kc].w;
    }
  }
  if (t < N) {
    nbrL[t] = nbr4[t];
    degL[t] = degg[t];
    cntL[t] = cntg[t];
    if (LAST) cwL[t] = cwg[t];
  }
  __syncthreads();

  // upd GEMM: lane = i, wave-uniform d-chunk
  const int i  = t & 63;
  const int d0 = __builtin_amdgcn_readfirstlane(t >> 6) * 16;

  float acc[16];
#pragma unroll
  for (int u = 0; u < 16; ++u) acc[u] = bu[d0 + u];

#pragma unroll 4
  for (int k = 0; k < 2 * D; ++k) {
    const float a = catT[k][i];
    const float* __restrict__ wr = Wu + (size_t)k * D + d0;
#pragma unroll
    for (int u = 0; u < 16; ++u) acc[u] += a * wr[u];
  }
#pragma unroll
  for (int u = 0; u < 16; ++u)
    sb[i][d0 + u] = 0.9f * acc[u] + 0.1f * catT[d0 + u][i];
  __syncthreads();

  // sequential scan; lane d owns column d of sb (wave 0 only)
  if (t < N) {
    const int d = t;
    uint4 w  = nbrL[0];
    int   c  = cntL[0];
    float dg = degL[0];
    for (int ii = 0; ii < N; ++ii) {
      uint4 wn = w; int cn = c; float dgn = dg;
      if (ii < N - 1) {
        wn  = nbrL[ii + 1];
        cn  = cntL[ii + 1];
        dgn = degL[ii + 1];
      }
      const unsigned wd[4] = {w.x, w.y, w.z, w.w};
      float nb = 0.0f;
#pragma unroll
      for (int q = 0; q < 8; ++q) {
        const int idx = (int)((wd[q >> 2] >> ((q & 3) * 8)) & 63u);
        const float v = sb[idx][d];
        nb += (q < c) ? v : 0.0f;
      }
      if (c > 8) {
#pragma unroll
        for (int q = 8; q < 16; ++q) {
          const int idx = (int)((wd[q >> 2] >> ((q & 3) * 8)) & 63u);
          const float v = sb[idx][d];
          nb += (q < c) ? v : 0.0f;
        }
        for (int q = 16; q < c; ++q) nb += sb[nfull[ii * N + q]][d];  // rare
      }
      const float avg = nb / fmaxf(dg, 1.0f);
      const float cur = sb[ii][d];
      sb[ii][d] = (dg > 0.0f) ? (0.95f * cur + 0.05f * avg) : cur;
      w = wn; c = cn; dg = dgn;
    }
    if (LAST) {
      float g = 0.0f;
      for (int i2 = 0; i2 < N; ++i2) g += cwL[i2] * sb[i2][d];

      float o = bo[d];
      for (int k2 = 0; k2 < D; ++k2) o += __shfl(g, k2, 64) * Wo[k2 * D + d];
      out[(size_t)b * D + d] = o;
    }
  }

  if (!LAST) {
    __syncthreads();
    const int ii = t >> 2;
    const int q  = t & 3;
    float* ps = s + ((size_t)b * N + ii) * D;
#pragma unroll
    for (int kc = 0; kc < 4; ++kc) {
      const int k0 = kc * 16 + q * 4;
      float4 v;
      v.x = sb[ii][k0 + 0];
      v.y = sb[ii][k0 + 1];
      v.z = sb[ii][k0 + 2];
      v.w = sb[ii][k0 + 3];
      *(float4*)(ps + k0) = v;
    }
  }
}

}  // namespace

extern "C" void kernel_launch(void* const* d_in, const int* in_sizes, int n_in,
                              void* d_out, int out_size, void* d_ws, size_t ws_size,
                              hipStream_t stream)
{
  const float* x  = (const float*)d_in[0];
  const float* ew = (const float*)d_in[1];
  const float* Wm = (const float*)d_in[2];
  const float* bm = (const float*)d_in[3];
  const float* Wu = (const float*)d_in[4];
  const float* bu = (const float*)d_in[5];
  const float* Wo = (const float*)d_in[6];
  const float* bo = (const float*)d_in[7];
  float* out = (float*)d_out;

  float* s = (float*)d_ws;
  uint4* nbr4 = (uint4*)(s + BND);                    // [N]
  float* degf = (float*)(nbr4 + N);                   // [N]
  float* cwg  = degf + N;                             // [N]
  int*   cntg = (int*)(cwg + N);                      // [N]
  int*   rowbaseg = cntg + N;                         // [N]
  unsigned char* nfull = (unsigned char*)(rowbaseg + N);  // [N][N]
  int*   slotIdx = (int*)(nfull + N * N);             // [N][N]
  float* msg = (float*)(slotIdx + N * N);             // [slots][B][D]

  const int L = in_sizes[2] / (N * N * E * D);  // = 3

  k_prep<<<1, 64, 0, stream>>>(ew, nbr4, degf, cwg, cntg, rowbaseg,
                               nfull, slotIdx);

  for (int l = 0; l < L; ++l) {
    const float* sin_p = (l == 0) ? x : s;
    k_msg<<<N * N, 256, 0, stream>>>(
        sin_p, ew,
        Wm + (size_t)l * N * N * E * D,
        bm + (size_t)l * N * N * D,
        slotIdx, msg);
    if (l < L - 1) {
      k_upd<false><<<B, 256, 0, stream>>>(
          sin_p, s, msg, nbr4, degf, cwg, cntg, rowbaseg, nfull,
          Wu + (size_t)l * 2 * D * D, bu + (size_t)l * D,
          Wo, bo, out);
    } else {
      k_upd<true><<<B, 256, 0, stream>>>(
          sin_p, s, msg, nbr4, degf, cwg, cntg, rowbaseg, nfull,
          Wu + (size_t)l * 2 * D * D, bu + (size_t)l * D,
          Wo, bo, out);
    }
  }
}

// Round 6
// 180.297 us; speedup vs baseline: 2.5910x; 1.1165x over previous
//
#include <hip/hip_runtime.h>

namespace {

constexpr int B = 64;
constexpr int N = 64;
constexpr int D = 64;
constexpr int E = 2 * D + 1;  // 129
constexpr int BND = B * N * D;

// Runs once: adjacency tables, readout weights, edge->slot mapping.
// Slots row-major: node i's edges are slots rowbase[i]..rowbase[i]+cnt[i]-1.
__global__ __launch_bounds__(64) void k_prep(
    const float* __restrict__ ew,   // [N][N]
    uint4* __restrict__ nbr4,       // [N] 16 packed neighbor ids (bytes)
    float* __restrict__ degf,       // [N]
    float* __restrict__ cwg,        // [N] readout weights
    int* __restrict__ cntg,         // [N]
    int* __restrict__ rowbaseg,     // [N]
    unsigned char* __restrict__ nfull,  // [N][N] full list (tail fallback)
    int* __restrict__ slotIdx)      // [N][N] edge slot (valid where ew>0)
{
  const int t = threadIdx.x;  // 0..63 = node

  int rc = 0;
  for (int j = 0; j < N; ++j) rc += (ew[t * N + j] > 0.0f) ? 1 : 0;
  int pre = rc;
#pragma unroll
  for (int off = 1; off < 64; off <<= 1) {
    int v = __shfl_up(pre, off, 64);
    if (t >= off) pre += v;
  }
  const int base = pre - rc;  // exclusive prefix
  rowbaseg[t] = base;

  unsigned long long lo = 0ull, hi = 0ull;
  int c = 0;
  float rowsum = 0.0f;
  for (int j = 0; j < N; ++j) {
    const float v = ew[t * N + j];
    rowsum += v;
    if (v > 0.0f) {
      slotIdx[t * N + j] = base + c;
      if (c < 8)       lo |= (unsigned long long)j << (c * 8);
      else if (c < 16) hi |= (unsigned long long)j << ((c - 8) * 8);
      nfull[t * N + c] = (unsigned char)j;
      ++c;
    }
  }
  uint4 w;
  w.x = (unsigned)(lo & 0xffffffffu);
  w.y = (unsigned)(lo >> 32);
  w.z = (unsigned)(hi & 0xffffffffu);
  w.w = (unsigned)(hi >> 32);
  nbr4[t] = w;
  cntg[t] = c;
  degf[t] = (float)c;

  float tot = rowsum;
#pragma unroll
  for (int off = 32; off >= 1; off >>= 1) tot += __shfl_xor(tot, off, 64);
  cwg[t] = rowsum / (tot + 1e-8f);
}

// Grid N*N; block 256. One block per (i,j); early-exit on non-edge.
// GEMM form: msg[b][d] = sum_k A[b][k] * W'[k][d] + (w*W'[2D][d] + bias[d]),
// A = [S_i | S_j] staged transposed in LDS, W' (32KB) staged in LDS via
// coalesced vector loads. Thread (tb,td) computes the 4x4 tile
// rows 4tb..4tb+3, cols 4td..4td+3. Plain stores to msg (no atomics).
__global__ __launch_bounds__(256) void k_msg(
    const float* __restrict__ sin,   // [B][N][D]
    const float* __restrict__ ew,    // [N][N]
    const float* __restrict__ Wm,    // [N][N][E][D]  (layer slice)
    const float* __restrict__ bm,    // [N][N][D]     (layer slice)
    const int* __restrict__ slotIdx, // [N][N]
    float* __restrict__ msg)         // [slot][B][D]
{
  const int ij = blockIdx.x;
  const float w = ew[ij];
  if (w == 0.0f) return;  // uniform across block
  const int i = ij >> 6;
  const int j = ij & 63;

  __shared__ float aT[2 * D][B];   // aT[k][b]: k<64 -> s_i, k>=64 -> s_j
  __shared__ float wL[2 * D * D];  // W' rows 0..127 flat (32KB)

  const int t = threadIdx.x;
  const float* __restrict__ Wp = Wm + (size_t)ij * (E * D);

  // stage W': 8192 contiguous floats, 8 float4 per thread, fully coalesced
#pragma unroll
  for (int r = 0; r < 8; ++r) {
    const int idx = (r * 256 + t) * 4;
    *(float4*)(wL + idx) = *(const float4*)(Wp + idx);
  }

  // stage A transposed
  {
    const int bb = t >> 2;   // 0..63
    const int q  = t & 3;    // 0..3
    const float* ps = sin + ((size_t)bb * N + i) * D;
    const float* pq = sin + ((size_t)bb * N + j) * D;
#pragma unroll
    for (int kc = 0; kc < 4; ++kc) {
      const int k0 = kc * 16 + q * 4;
      float4 v = *(const float4*)(ps + k0);
      aT[k0 + 0][bb] = v.x;
      aT[k0 + 1][bb] = v.y;
      aT[k0 + 2][bb] = v.z;
      aT[k0 + 3][bb] = v.w;
      float4 u2 = *(const float4*)(pq + k0);
      aT[D + k0 + 0][bb] = u2.x;
      aT[D + k0 + 1][bb] = u2.y;
      aT[D + k0 + 2][bb] = u2.z;
      aT[D + k0 + 3][bb] = u2.w;
    }
  }
  __syncthreads();

  const int td = t & 15;   // col tile: d = 4*td .. +4
  const int tb = t >> 4;   // row tile: b = 4*tb .. +4

  // init: w * W'[2D][d] + bias[d] (d-only), replicated across rows
  const float4 wi = *(const float4*)(Wp + (size_t)(2 * D) * D + td * 4);
  const float4 bi = *(const float4*)(bm + (size_t)ij * D + td * 4);
  float4 base;
  base.x = w * wi.x + bi.x;
  base.y = w * wi.y + bi.y;
  base.z = w * wi.z + bi.z;
  base.w = w * wi.w + bi.w;

  float acc[4][4];
#pragma unroll
  for (int r = 0; r < 4; ++r) {
    acc[r][0] = base.x; acc[r][1] = base.y;
    acc[r][2] = base.z; acc[r][3] = base.w;
  }

#pragma unroll 4
  for (int k = 0; k < 2 * D; ++k) {
    const float4 a  = *(const float4*)&aT[k][tb * 4];
    const float4 wv = *(const float4*)(wL + k * D + td * 4);
    const float ar[4] = {a.x, a.y, a.z, a.w};
    const float wc[4] = {wv.x, wv.y, wv.z, wv.w};
#pragma unroll
    for (int r = 0; r < 4; ++r)
#pragma unroll
      for (int c = 0; c < 4; ++c)
        acc[r][c] += ar[r] * wc[c];
  }

  const int slot = slotIdx[ij];
  float* mp = msg + ((size_t)slot * B + tb * 4) * D + td * 4;
#pragma unroll
  for (int r = 0; r < 4; ++r) {
    float4 v;
    v.x = acc[r][0]; v.y = acc[r][1]; v.z = acc[r][2]; v.w = acc[r][3];
    *(float4*)(mp + (size_t)r * D) = v;
  }
}

// One block per batch b: sums neighbor msg slots during staging, update MLP +
// residual mix, sequential node scan in LDS. LAST fuses readout + projection.
template <bool LAST>
__global__ __launch_bounds__(256) void k_upd(
    const float* __restrict__ sin,  // [B][N][D]
    float* __restrict__ s,          // [B][N][D] out (non-LAST)
    const float* __restrict__ msg,  // [slot][B][D]
    const uint4* __restrict__ nbr4,
    const float* __restrict__ degg,
    const float* __restrict__ cwg,
    const int* __restrict__ cntg,
    const int* __restrict__ rowbaseg,
    const unsigned char* __restrict__ nfull,
    const float* __restrict__ Wu,   // [2D][D] (layer slice)
    const float* __restrict__ bu,   // [D]
    const float* __restrict__ Wo,   // [D][D]
    const float* __restrict__ bo,   // [D]
    float* __restrict__ out)        // [B][D]
{
  const int b = blockIdx.x;
  const int t = threadIdx.x;

  __shared__ float catT[2 * D][N];   // catT[k][i]: k<D -> sin, k>=D -> agg
  __shared__ float sb[N][D + 1];     // padded scan state
  __shared__ uint4 nbrL[N];
  __shared__ float degL[N];
  __shared__ float cwL[N];
  __shared__ int   cntL[N];

  {
    const int ii = t >> 2;
    const int q  = t & 3;
    const float* ps = sin + ((size_t)b * N + ii) * D;
    const int cI = cntg[ii];
    const int rb = rowbaseg[ii];

    float4 a4[4] = {make_float4(0.f, 0.f, 0.f, 0.f),
                    make_float4(0.f, 0.f, 0.f, 0.f),
                    make_float4(0.f, 0.f, 0.f, 0.f),
                    make_float4(0.f, 0.f, 0.f, 0.f)};
    for (int e = 0; e < cI; ++e) {
      const float* pm = msg + ((size_t)(rb + e) * B + b) * D;
#pragma unroll
      for (int kc = 0; kc < 4; ++kc) {
        const float4 v = *(const float4*)(pm + kc * 16 + q * 4);
        a4[kc].x += v.x; a4[kc].y += v.y; a4[kc].z += v.z; a4[kc].w += v.w;
      }
    }
#pragma unroll
    for (int kc = 0; kc < 4; ++kc) {
      const int k0 = kc * 16 + q * 4;
      float4 v = *(const float4*)(ps + k0);
      catT[k0 + 0][ii] = v.x;
      catT[k0 + 1][ii] = v.y;
      catT[k0 + 2][ii] = v.z;
      catT[k0 + 3][ii] = v.w;
      catT[D + k0 + 0][ii] = a4[kc].x;
      catT[D + k0 + 1][ii] = a4[kc].y;
      catT[D + k0 + 2][ii] = a4[kc].z;
      catT[D + k0 + 3][ii] = a4[kc].w;
    }
  }
  if (t < N) {
    nbrL[t] = nbr4[t];
    degL[t] = degg[t];
    cntL[t] = cntg[t];
    if (LAST) cwL[t] = cwg[t];
  }
  __syncthreads();

  // upd GEMM: lane = i, wave-uniform d-chunk
  const int i  = t & 63;
  const int d0 = __builtin_amdgcn_readfirstlane(t >> 6) * 16;

  float acc[16];
#pragma unroll
  for (int u = 0; u < 16; ++u) acc[u] = bu[d0 + u];

#pragma unroll 4
  for (int k = 0; k < 2 * D; ++k) {
    const float a = catT[k][i];
    const float* __restrict__ wr = Wu + (size_t)k * D + d0;
#pragma unroll
    for (int u = 0; u < 16; ++u) acc[u] += a * wr[u];
  }
#pragma unroll
  for (int u = 0; u < 16; ++u)
    sb[i][d0 + u] = 0.9f * acc[u] + 0.1f * catT[d0 + u][i];
  __syncthreads();

  // sequential scan; lane d owns column d of sb (wave 0 only)
  if (t < N) {
    const int d = t;
    uint4 w  = nbrL[0];
    int   c  = cntL[0];
    float dg = degL[0];
    for (int ii = 0; ii < N; ++ii) {
      uint4 wn = w; int cn = c; float dgn = dg;
      if (ii < N - 1) {
        wn  = nbrL[ii + 1];
        cn  = cntL[ii + 1];
        dgn = degL[ii + 1];
      }
      const unsigned wd[4] = {w.x, w.y, w.z, w.w};
      float nb = 0.0f;
#pragma unroll
      for (int q = 0; q < 8; ++q) {
        const int idx = (int)((wd[q >> 2] >> ((q & 3) * 8)) & 63u);
        const float v = sb[idx][d];
        nb += (q < c) ? v : 0.0f;
      }
      if (c > 8) {
#pragma unroll
        for (int q = 8; q < 16; ++q) {
          const int idx = (int)((wd[q >> 2] >> ((q & 3) * 8)) & 63u);
          const float v = sb[idx][d];
          nb += (q < c) ? v : 0.0f;
        }
        for (int q = 16; q < c; ++q) nb += sb[nfull[ii * N + q]][d];  // rare
      }
      const float avg = nb / fmaxf(dg, 1.0f);
      const float cur = sb[ii][d];
      sb[ii][d] = (dg > 0.0f) ? (0.95f * cur + 0.05f * avg) : cur;
      w = wn; c = cn; dg = dgn;
    }
    if (LAST) {
      float g = 0.0f;
      for (int i2 = 0; i2 < N; ++i2) g += cwL[i2] * sb[i2][d];

      float o = bo[d];
      for (int k2 = 0; k2 < D; ++k2) o += __shfl(g, k2, 64) * Wo[k2 * D + d];
      out[(size_t)b * D + d] = o;
    }
  }

  if (!LAST) {
    __syncthreads();
    const int ii = t >> 2;
    const int q  = t & 3;
    float* ps = s + ((size_t)b * N + ii) * D;
#pragma unroll
    for (int kc = 0; kc < 4; ++kc) {
      const int k0 = kc * 16 + q * 4;
      float4 v;
      v.x = sb[ii][k0 + 0];
      v.y = sb[ii][k0 + 1];
      v.z = sb[ii][k0 + 2];
      v.w = sb[ii][k0 + 3];
      *(float4*)(ps + k0) = v;
    }
  }
}

}  // namespace

extern "C" void kernel_launch(void* const* d_in, const int* in_sizes, int n_in,
                              void* d_out, int out_size, void* d_ws, size_t ws_size,
                              hipStream_t stream)
{
  const float* x  = (const float*)d_in[0];
  const float* ew = (const float*)d_in[1];
  const float* Wm = (const float*)d_in[2];
  const float* bm = (const float*)d_in[3];
  const float* Wu = (const float*)d_in[4];
  const float* bu = (const float*)d_in[5];
  const float* Wo = (const float*)d_in[6];
  const float* bo = (const float*)d_in[7];
  float* out = (float*)d_out;

  float* s = (float*)d_ws;
  uint4* nbr4 = (uint4*)(s + BND);                    // [N]
  float* degf = (float*)(nbr4 + N);                   // [N]
  float* cwg  = degf + N;                             // [N]
  int*   cntg = (int*)(cwg + N);                      // [N]
  int*   rowbaseg = cntg + N;                         // [N]
  unsigned char* nfull = (unsigned char*)(rowbaseg + N);  // [N][N]
  int*   slotIdx = (int*)(nfull + N * N);             // [N][N]
  float* msg = (float*)(slotIdx + N * N);             // [slots][B][D]

  const int L = in_sizes[2] / (N * N * E * D);  // = 3

  k_prep<<<1, 64, 0, stream>>>(ew, nbr4, degf, cwg, cntg, rowbaseg,
                               nfull, slotIdx);

  for (int l = 0; l < L; ++l) {
    const float* sin_p = (l == 0) ? x : s;
    k_msg<<<N * N, 256, 0, stream>>>(
        sin_p, ew,
        Wm + (size_t)l * N * N * E * D,
        bm + (size_t)l * N * N * D,
        slotIdx, msg);
    if (l < L - 1) {
      k_upd<false><<<B, 256, 0, stream>>>(
          sin_p, s, msg, nbr4, degf, cwg, cntg, rowbaseg, nfull,
          Wu + (size_t)l * 2 * D * D, bu + (size_t)l * D,
          Wo, bo, out);
    } else {
      k_upd<true><<<B, 256, 0, stream>>>(
          sin_p, s, msg, nbr4, degf, cwg, cntg, rowbaseg, nfull,
          Wu + (size_t)l * 2 * D * D, bu + (size_t)l * D,
          Wo, bo, out);
    }
  }
}